// Round 7
// baseline (380.566 us; speedup 1.0000x reference)
//
#include <hip/hip_runtime.h>
#include <hip/hip_bf16.h>

#define NN 100000
#define NE 1280000
#define DD 64
#define NRANGE 98            // ceil(NN/1024)
#define NGROUPS (NN / 16)    // 6250
#define GG 1536              // persistent gemm grid (6 blocks/CU)

typedef __attribute__((ext_vector_type(8))) short bf16x8;
typedef __attribute__((ext_vector_type(4))) float f32x4;

static __device__ __forceinline__ unsigned short f2bf(float f) {
    __hip_bfloat16 h = __float2bfloat16(f);
    return *reinterpret_cast<unsigned short*>(&h);
}

// ---------------------------------------------------------------------------
// x (fp32) -> bf16 copy. Grid 6250 x 256, 4 elems/thread (exact: 6.4M).
// ---------------------------------------------------------------------------
__global__ __launch_bounds__(256) void f32_to_bf16_kernel(
    const float* __restrict__ in, unsigned short* __restrict__ out)
{
    int i = (blockIdx.x * 256 + threadIdx.x) * 4;
    float4 v = *(const float4*)(in + i);
    ushort4 o;
    o.x = f2bf(v.x); o.y = f2bf(v.y); o.z = f2bf(v.z); o.w = f2bf(v.w);
    *(ushort4*)(out + i) = o;
}

// ---------------------------------------------------------------------------
// Range histogram: count edges per 1024-node dst range. LDS-staged.
// ---------------------------------------------------------------------------
__global__ __launch_bounds__(256) void hist2_kernel(
    const int* __restrict__ dst, int* __restrict__ rangeCnt)
{
    __shared__ int h[128];
    int tid = threadIdx.x;
    if (tid < 128) h[tid] = 0;
    __syncthreads();
    int e0 = blockIdx.x * 1024 + tid * 4;
    int4 d4 = *(const int4*)(dst + e0);
    atomicAdd(&h[d4.x >> 10], 1);
    atomicAdd(&h[d4.y >> 10], 1);
    atomicAdd(&h[d4.z >> 10], 1);
    atomicAdd(&h[d4.w >> 10], 1);
    __syncthreads();
    if (tid < NRANGE && h[tid]) atomicAdd(&rangeCnt[tid], h[tid]);
}

// ---------------------------------------------------------------------------
// Exclusive scan of 98 range counts -> rangeBase[99] + gcur (P1 cursors).
// ---------------------------------------------------------------------------
__global__ __launch_bounds__(128) void scan98_kernel(
    const int* __restrict__ rangeCnt, int* __restrict__ rangeBase,
    int* __restrict__ gcur, int* __restrict__ rowptr)
{
    __shared__ int sd[128];
    int tid = threadIdx.x;
    int v = (tid < NRANGE) ? rangeCnt[tid] : 0;
    sd[tid] = v;
    __syncthreads();
    for (int o = 1; o < 128; o <<= 1) {
        int t = (tid >= o) ? sd[tid - o] : 0;
        __syncthreads();
        sd[tid] += t;
        __syncthreads();
    }
    if (tid < NRANGE) { int ex = sd[tid] - v; rangeBase[tid] = ex; gcur[tid] = ex; }
    if (tid == 0) { rangeBase[NRANGE] = NE; rowptr[NN] = NE; }
}

// ---------------------------------------------------------------------------
// P1: coarse bin by dst range, block-synchronous LDS staging (grouped runs).
// ---------------------------------------------------------------------------
__global__ __launch_bounds__(256) void p1_bin_kernel(
    const int* __restrict__ src, const int* __restrict__ dst,
    const float* __restrict__ w, int* __restrict__ gcur,
    int2* __restrict__ ecoarse)
{
    __shared__ int2 stage[1024];
    __shared__ unsigned char sbkt[1024];
    __shared__ int cnt[128], ofs[128], gpos[128], sd[128];

    int tid = threadIdx.x;
    int e0 = blockIdx.x * 1024 + tid * 4;
    int4   s4 = *(const int4*)(src + e0);
    int4   d4 = *(const int4*)(dst + e0);
    float4 w4 = *(const float4*)(w + e0);

    if (tid < 128) cnt[tid] = 0;
    __syncthreads();

    int ss[4] = {s4.x, s4.y, s4.z, s4.w};
    int dd[4] = {d4.x, d4.y, d4.z, d4.w};
    float ww[4] = {w4.x, w4.y, w4.z, w4.w};
    int b[4], p[4];
#pragma unroll
    for (int i = 0; i < 4; ++i) {
        b[i] = dd[i] >> 10;
        p[i] = atomicAdd(&cnt[b[i]], 1);
    }
    __syncthreads();

    int cv = (tid < 128) ? cnt[tid] : 0;
    if (tid < 128) sd[tid] = cv;
    __syncthreads();
    for (int o = 1; o < 128; o <<= 1) {
        int t = (tid >= o && tid < 128) ? sd[tid - o] : 0;
        __syncthreads();
        if (tid < 128) sd[tid] += t;
        __syncthreads();
    }
    if (tid < 128) ofs[tid] = sd[tid] - cv;
    if (tid < NRANGE && cv > 0) gpos[tid] = atomicAdd(&gcur[tid], cv);
    __syncthreads();

#pragma unroll
    for (int i = 0; i < 4; ++i) {
        int slot = ofs[b[i]] + p[i];
        stage[slot] = make_int2(ss[i] | ((dd[i] & 1023) << 17), __float_as_int(ww[i]));
        sbkt[slot] = (unsigned char)b[i];
    }
    __syncthreads();

    for (int j = tid; j < 1024; j += 256) {
        int bb = sbkt[j];
        ecoarse[gpos[bb] + (j - ofs[bb])] = stage[j];
    }
}

// ---------------------------------------------------------------------------
// P2: per-range degree count + LDS scan -> rowptr, then place into the
// range's L2-resident ebuf window. Grid NRANGE.
// ---------------------------------------------------------------------------
__global__ __launch_bounds__(256) void p2_place_kernel(
    const int2* __restrict__ ecoarse, const int* __restrict__ rangeBase,
    int* __restrict__ rowptr, int2* __restrict__ ebuf)
{
    __shared__ int cnt[1024];
    __shared__ int ssum[256];
    int r = blockIdx.x, tid = threadIdx.x;
    int beg = rangeBase[r], end = rangeBase[r + 1];

    for (int i = tid; i < 1024; i += 256) cnt[i] = 0;
    __syncthreads();

    for (int j = beg + tid; j < end; j += 256) {
        int2 rec = ecoarse[j];
        atomicAdd(&cnt[(rec.x >> 17) & 1023], 1);
    }
    __syncthreads();

    int base4 = tid * 4;
    int c0 = cnt[base4], c1 = cnt[base4 + 1], c2 = cnt[base4 + 2], c3 = cnt[base4 + 3];
    int s = c0 + c1 + c2 + c3;
    ssum[tid] = s;
    __syncthreads();
    for (int o = 1; o < 256; o <<= 1) {
        int t = (tid >= o) ? ssum[tid - o] : 0;
        __syncthreads();
        ssum[tid] += t;
        __syncthreads();
    }
    int p0 = beg + ssum[tid] - s;
    int p1 = p0 + c0, p2 = p1 + c1, p3 = p2 + c2;

    int node0 = (r << 10) + base4;
    if (node0 < NN)     rowptr[node0]     = p0;
    if (node0 + 1 < NN) rowptr[node0 + 1] = p1;
    if (node0 + 2 < NN) rowptr[node0 + 2] = p2;
    if (node0 + 3 < NN) rowptr[node0 + 3] = p3;
    cnt[base4] = p0; cnt[base4 + 1] = p1; cnt[base4 + 2] = p2; cnt[base4 + 3] = p3;
    __syncthreads();

    for (int j = beg + tid; j < end; j += 256) {
        int2 rec = ecoarse[j];
        int dl = (rec.x >> 17) & 1023;
        int p = atomicAdd(&cnt[dl], 1);
        ebuf[p] = make_int2(rec.x & 0x1FFFF, rec.y);
    }
}

// ---------------------------------------------------------------------------
// CSR gather, MLP-wide: wave per node. Lane layout q=lane>>4 (edge sub-slot),
// f4=lane&15 (feature quad). One 16-edge body = 4 record loads + 4 row loads
// (uint2 = 4 features/lane), ALL independent -> ~2 dependent round trips per
// node instead of ~6. Invalid slots clamped (weight 0, index beg, L1-hot).
// Final: shfl_xor(16,32) reduce; lanes 0-15 store the 128 B bf16 row.
// Grid 25000 (exact).
// ---------------------------------------------------------------------------
__global__ __launch_bounds__(256) void csr_agg_bf16_kernel(
    const unsigned short* __restrict__ hb, const int* __restrict__ rowptr,
    const int2* __restrict__ ebuf, unsigned short* __restrict__ aggb)
{
    int lane = threadIdx.x & 63;
    int node = blockIdx.x * 4 + (threadIdx.x >> 6);
    int beg = __builtin_amdgcn_readfirstlane(rowptr[node]);
    int end = __builtin_amdgcn_readfirstlane(rowptr[node + 1]);

    int q  = lane >> 4;    // edge sub-slot 0..3
    int f4 = lane & 15;    // feature quad: features 4*f4 .. 4*f4+3

    float ax = 0.f, ay = 0.f, az = 0.f, aw = 0.f;

    for (int j = beg; j < end; j += 16) {
#pragma unroll
        for (int s = 0; s < 4; ++s) {
            int e = j + s * 4 + q;
            bool valid = (e < end);
            int ec = valid ? e : beg;
            int2 rec = ebuf[ec];
            float wv = valid ? __int_as_float(rec.y) : 0.f;
            uint2 u = *(const uint2*)(hb + (size_t)rec.x * DD + f4 * 4);
            ax = fmaf(wv, __uint_as_float(u.x << 16), ax);
            ay = fmaf(wv, __uint_as_float(u.x & 0xFFFF0000u), ay);
            az = fmaf(wv, __uint_as_float(u.y << 16), az);
            aw = fmaf(wv, __uint_as_float(u.y & 0xFFFF0000u), aw);
        }
    }

    // reduce across the 4 edge sub-slots (lanes q=0..3 hold partials)
    ax += __shfl_xor(ax, 16); ax += __shfl_xor(ax, 32);
    ay += __shfl_xor(ay, 16); ay += __shfl_xor(ay, 32);
    az += __shfl_xor(az, 16); az += __shfl_xor(az, 32);
    aw += __shfl_xor(aw, 16); aw += __shfl_xor(aw, 32);

    if (lane < 16) {
        ushort4 o;
        o.x = f2bf(ax); o.y = f2bf(ay); o.z = f2bf(az); o.w = f2bf(aw);
        *(ushort4*)(aggb + (size_t)node * DD + f4 * 4) = o;
    }
}

// ---------------------------------------------------------------------------
// MFMA dual GEMM (persistent): out16[g*16..][n] = [aggb|hb] @ [Wrel;Wroot]
// + bias (+ReLU). B fragments in registers (loaded once); A staged to LDS in
// fragment order (double-buffered, 1 barrier/group); 4 MFMA/wave/group.
// ---------------------------------------------------------------------------
template <bool RELU, bool OUT32>
__global__ __launch_bounds__(256) void mfma_gemm_kernel(
    const unsigned short* __restrict__ aggb,
    const unsigned short* __restrict__ hb,
    const float* __restrict__ Wrel,
    const float* __restrict__ brel,
    const float* __restrict__ Wroot,
    void* __restrict__ outp)
{
    __shared__ __align__(16) unsigned short Ast[2][256][8];   // 8 KB

    int tid = threadIdx.x;
    int lane = tid & 63;
    int wv = tid >> 6;            // wave = N-tile (cols 16w..16w+16)
    int quad = lane >> 4;
    int m16 = lane & 15;
    int n = wv * 16 + m16;        // this lane's output column

    // ---- B fragments (static weights) into registers: 4 ksteps x 8 bf16
    bf16x8 bfrag[4];
#pragma unroll
    for (int t = 0; t < 4; ++t) {
#pragma unroll
        for (int j = 0; j < 8; ++j) {
            int k = t * 32 + quad * 8 + j;
            float wval = (k < 64) ? Wrel[k * 64 + n] : Wroot[(k - 64) * 64 + n];
            bfrag[t][j] = (short)f2bf(wval);
        }
    }
    float bias = brel[n];

    // staging role: kstep ts, row ms, col base c0 (8 bf16 = 16B per thread)
    int ts = tid >> 6;
    int ls = tid & 63;
    int ms = ls & 15;
    int c0 = ts * 32 + (ls >> 4) * 8;
    bool fromAgg = (c0 < 64);
    int cOff = fromAgg ? c0 : (c0 - 64);

    int g = blockIdx.x;
    int buf = 0;
    while (g < NGROUPS) {
        {
            size_t row = (size_t)g * 16 + ms;
            const unsigned short* sp = (fromAgg ? aggb : hb) + row * DD + cOff;
            *(uint4*)&Ast[buf][tid][0] = *(const uint4*)sp;
        }
        __syncthreads();

        f32x4 c = {0.f, 0.f, 0.f, 0.f};
#pragma unroll
        for (int t = 0; t < 4; ++t) {
            bf16x8 a = *(const bf16x8*)&Ast[buf][t * 64 + lane][0];
            c = __builtin_amdgcn_mfma_f32_16x16x32_bf16(a, bfrag[t], c, 0, 0, 0);
        }

#pragma unroll
        for (int reg = 0; reg < 4; ++reg) {
            int row = quad * 4 + reg;
            size_t node = (size_t)g * 16 + row;
            float v = c[reg] + bias;
            if (RELU) v = fmaxf(v, 0.f);
            if (OUT32) ((float*)outp)[node * DD + n] = v;
            else       ((unsigned short*)outp)[node * DD + n] = f2bf(v);
        }
        g += GG;
        buf ^= 1;
    }
}

extern "C" void kernel_launch(void* const* d_in, const int* in_sizes, int n_in,
                              void* d_out, int out_size, void* d_ws, size_t ws_size,
                              hipStream_t stream)
{
    const float* x     = (const float*)d_in[0];
    const int*   ei    = (const int*)d_in[1];
    const float* w     = (const float*)d_in[2];
    const float* Wrel1 = (const float*)d_in[4];
    const float* brel1 = (const float*)d_in[5];
    const float* Wroot1= (const float*)d_in[6];
    const float* Wrel2 = (const float*)d_in[7];
    const float* brel2 = (const float*)d_in[8];
    const float* Wroot2= (const float*)d_in[9];
    const float* Wrel3 = (const float*)d_in[10];
    const float* brel3 = (const float*)d_in[11];
    const float* Wroot3= (const float*)d_in[12];

    float* out = (float*)d_out;

    // workspace: ebuf | region2 (ecoarse -> xb, after build) | aggb | hb | ints
    char* ws = (char*)d_ws;
    int2*  ebuf    = (int2*)ws;                       ws += (size_t)NE * 8;          // 10.24 MB
    int2*  ecoarse = (int2*)ws;
    unsigned short* xb = (unsigned short*)ws;         ws += (size_t)NN * DD * 2;     // 12.8 MB (>= ecoarse 10.24)
    unsigned short* aggb = (unsigned short*)ws;       ws += (size_t)NN * DD * 2;     // 12.8 MB
    unsigned short* hb = (unsigned short*)ws;         ws += (size_t)NN * DD * 2;     // 12.8 MB
    int*   rowptr  = (int*)ws;                        ws += (size_t)(NN + 1) * 4;
    int*   rangeCnt = (int*)ws;                       ws += (size_t)128 * 4;
    int*   rangeBase = (int*)ws;                      ws += (size_t)128 * 4;
    int*   gcur    = (int*)ws;

    const int* src = ei;
    const int* dst = ei + NE;

    // ---- CSR build (ecoarse region reused as xb afterwards) ----
    hipMemsetAsync(rangeCnt, 0, NRANGE * 4, stream);
    hist2_kernel<<<1250, 256, 0, stream>>>(dst, rangeCnt);
    scan98_kernel<<<1, 128, 0, stream>>>(rangeCnt, rangeBase, gcur, rowptr);
    p1_bin_kernel<<<1250, 256, 0, stream>>>(src, dst, w, gcur, ecoarse);
    p2_place_kernel<<<NRANGE, 256, 0, stream>>>(ecoarse, rangeBase, rowptr, ebuf);

    // ---- xb = bf16(x) (ecoarse dead now) ----
    f32_to_bf16_kernel<<<6250, 256, 0, stream>>>(x, xb);

    // ---- Layer 1: gather(xb)->aggb ; mfma([aggb|xb])->hb (bf16, ReLU) ----
    csr_agg_bf16_kernel<<<NN / 4, 256, 0, stream>>>(xb, rowptr, ebuf, aggb);
    mfma_gemm_kernel<true, false><<<GG, 256, 0, stream>>>(
        aggb, xb, Wrel1, brel1, Wroot1, hb);

    // ---- Layer 2: gather(hb)->aggb ; mfma([aggb|hb])->hb (bf16, ReLU) ----
    csr_agg_bf16_kernel<<<NN / 4, 256, 0, stream>>>(hb, rowptr, ebuf, aggb);
    mfma_gemm_kernel<true, false><<<GG, 256, 0, stream>>>(
        aggb, hb, Wrel2, brel2, Wroot2, hb);

    // ---- Layer 3: gather(hb)->aggb ; mfma([aggb|hb])->out (fp32) ----
    csr_agg_bf16_kernel<<<NN / 4, 256, 0, stream>>>(hb, rowptr, ebuf, aggb);
    mfma_gemm_kernel<false, true><<<GG, 256, 0, stream>>>(
        aggb, hb, Wrel3, brel3, Wroot3, out);
}